// Round 8
// baseline (613.739 us; speedup 1.0000x reference)
//
#include <hip/hip_runtime.h>

#define DF 128
#define MT 64          // rows per tile (edge)
#define MTS 32         // rows per block (pq/node)
#define LNEPS 1e-5f
#define NATOMS 20000
#define EGRID 768      // persistent edge blocks (3/CU x 256)

typedef __attribute__((ext_vector_type(8))) short short8;
typedef __attribute__((ext_vector_type(4))) float float4v;

// ---- module-global scratch ----
// Weights FRAGMENT-CONTIGUOUS: idx = ((kblk*8 + nb)*64 + lane)*8 + e
// value = W[i = kblk*32 + (lane>>4)*8 + e][o = nb*16 + (lane&15)]
#define EW0H 0
#define EW0L (EW0H + 384*128)
#define EW1H (EW0L + 384*128)
#define EW1L (EW1H + 128*128)
#define EW2H (EW1L + 128*128)
#define EW2L (EW2H + 128*128)
#define NW0H (EW2L + 128*128)
#define NW0L (NW0H + 128*128)
#define NW1H (NW0L + 128*128)
#define NW1L (NW1H + 128*128)
#define NW2H (NW1L + 128*128)
#define NW2L (NW2H + 128*128)
#define WTOT (NW2L + 128*128)   // 512 KB

__device__ short g_w[WTOT];
__device__ float g_nodein[NATOMS * DF];
__device__ float g_P[NATOMS * DF];        // x @ W0a (recv part)
__device__ float g_Q[NATOMS * DF];        // x @ W0b (send part)
__device__ float g_sgs[8], g_sbs[8];      // per-16-chunk sum(gamma), sum(beta)

__device__ __forceinline__ short f2bf(float f) {
    union { float f; unsigned u; } v; v.f = f;
    unsigned r = v.u + 0x7FFFu + ((v.u >> 16) & 1u);  // RNE
    return (short)(r >> 16);
}
__device__ __forceinline__ float bf2f(short s) {
    union { unsigned u; float f; } v; v.u = ((unsigned)(unsigned short)s) << 16;
    return v.f;
}
struct B2 { short hi, lo; };
__device__ __forceinline__ B2 f2b2(float v) {   // exact RNE split (wconv only)
    B2 r;
    r.hi = f2bf(v);
    r.lo = f2bf(v - bf2f(r.hi));
    return r;
}
// packed hi/lo split: 2 floats -> 2 packed u32 (hi-pair, lo-pair), RNE, ~6 VALU/2 floats
__device__ __forceinline__ void cvt2(float v0, float v1, unsigned& hp, unsigned& lp) {
    unsigned h;
    asm("v_cvt_pk_bf16_f32 %0, %1, %2" : "=v"(h) : "v"(v0), "v"(v1));
    union { unsigned u; float f; } h0, h1;
    h0.u = h << 16; h1.u = h & 0xFFFF0000u;
    const float l0 = v0 - h0.f, l1 = v1 - h1.f;
    unsigned l;
    asm("v_cvt_pk_bf16_f32 %0, %1, %2" : "=v"(l) : "v"(l0), "v"(l1));
    hp = h; lp = l;
}

// ---------------- weight convert: coalesced read, scattered (pipelined) write ----------------
struct WConvArgs {
    const float* W[6];
    int din[6];
    const float* g;
    const float* bt;
};

__global__ void wconv_all(WConvArgs a) {
    const int b = blockIdx.x;
    if (b == 512) {
        if (threadIdx.x < 8) {
            float sg = 0.f, sb = 0.f;
#pragma unroll
            for (int j = 0; j < 16; ++j) {
                sg += a.g[threadIdx.x * 16 + j];
                sb += a.bt[threadIdx.x * 16 + j];
            }
            g_sgs[threadIdx.x] = sg;
            g_sbs[threadIdx.x] = sb;
        }
        return;
    }
    const int baseh[6] = {EW0H, EW1H, EW2H, NW0H, NW1H, NW2H};
    const int dlo[6]   = {384*128, 128*128, 128*128, 128*128, 128*128, 128*128};
    int m, flat;
    if (b < 192) { m = 0; flat = b * 256 + threadIdx.x; }
    else { m = 1 + (b - 192) / 64; flat = ((b - 192) % 64) * 256 + threadIdx.x; }
    const int i = flat >> 7, o = flat & 127;          // coalesced read: o fastest
    const float w = a.W[m][(size_t)i * DF + o];
    const int kblk = i >> 5, quad = (i >> 3) & 3, e = i & 7;
    const int nb = o >> 4, lq = o & 15;
    const int idx = ((kblk * 8 + nb) * 64 + quad * 16 + lq) * 8 + e;
    B2 r = f2b2(w);
    g_w[baseh[m] + idx] = r.hi;
    g_w[baseh[m] + dlo[m] + idx] = r.lo;
}

// ---------------- per-wave MFMA tile: M = MTW*16 rows, N = NTW*16 cols ----------------
template<int MTW, int NTW>
__device__ __forceinline__ void mm_tile_t(float4v (&acc)[MTW][NTW],
                                          const short (*hi)[136], const short (*lo)[136],
                                          const short* __restrict__ Whi,
                                          const short* __restrict__ Wlo,
                                          int kblk0, int nb0, int quad, int lq)
{
    const int lane = quad * 16 + lq;
    const int base0 = ((kblk0 * 8 + nb0) * 64 + lane) * 8;
#pragma unroll
    for (int ks = 0; ks < 4; ++ks) {
        const int k0 = ks * 32 + quad * 8;
        short8 ah[MTW], al[MTW], bh[NTW], bl[NTW];
#pragma unroll
        for (int mt = 0; mt < MTW; ++mt) {
            ah[mt] = *(const short8*)&hi[mt * 16 + lq][k0];
            al[mt] = *(const short8*)&lo[mt * 16 + lq][k0];
        }
#pragma unroll
        for (int nt = 0; nt < NTW; ++nt) {
            const int off = base0 + ks * 4096 + nt * 512;
            bh[nt] = *(const short8*)(Whi + off);
            bl[nt] = *(const short8*)(Wlo + off);
        }
#pragma unroll
        for (int mt = 0; mt < MTW; ++mt)
#pragma unroll
            for (int nt = 0; nt < NTW; ++nt) {
                acc[mt][nt] = __builtin_amdgcn_mfma_f32_16x16x32_bf16(ah[mt], bh[nt], acc[mt][nt], 0, 0, 0);
                acc[mt][nt] = __builtin_amdgcn_mfma_f32_16x16x32_bf16(al[mt], bh[nt], acc[mt][nt], 0, 0, 0);
                acc[mt][nt] = __builtin_amdgcn_mfma_f32_16x16x32_bf16(ah[mt], bl[nt], acc[mt][nt], 0, 0, 0);
            }
    }
}

template<int MTW, int NTW>
__device__ __forceinline__ void relu_store_t(float4v (&acc)[MTW][NTW],
                                             short (*hi)[136], short (*lo)[136],
                                             const float (&bv)[NTW],
                                             int n0, int quad, int lq)
{
#pragma unroll
    for (int nt = 0; nt < NTW; ++nt) {
        const int c = n0 + nt * 16 + lq;
#pragma unroll
        for (int mt = 0; mt < MTW; ++mt) {
            const float v0 = fmaxf(acc[mt][nt][0] + bv[nt], 0.f);
            const float v1 = fmaxf(acc[mt][nt][1] + bv[nt], 0.f);
            const float v2 = fmaxf(acc[mt][nt][2] + bv[nt], 0.f);
            const float v3 = fmaxf(acc[mt][nt][3] + bv[nt], 0.f);
            unsigned h01, l01, h23, l23;
            cvt2(v0, v1, h01, l01);
            cvt2(v2, v3, h23, l23);
            const int r = mt * 16 + quad * 4;
            hi[r + 0][c] = (short)h01; hi[r + 1][c] = (short)(h01 >> 16);
            hi[r + 2][c] = (short)h23; hi[r + 3][c] = (short)(h23 >> 16);
            lo[r + 0][c] = (short)l01; lo[r + 1][c] = (short)(l01 >> 16);
            lo[r + 2][c] = (short)l23; lo[r + 3][c] = (short)(l23 >> 16);
            acc[mt][nt][0] = 0.f; acc[mt][nt][1] = 0.f;
            acc[mt][nt][2] = 0.f; acc[mt][nt][3] = 0.f;
        }
    }
}

// ---------------- P/Q precompute ----------------
__launch_bounds__(256, 4)
__global__ void pq_kernel(const float* __restrict__ x, int N)
{
    __shared__ short s_hi[MTS][136];
    __shared__ short s_lo[MTS][136];

    const int tid = threadIdx.x;
    const int wave = tid >> 6, lane = tid & 63;
    const int quad = lane >> 4, lq = lane & 15;
    const int n0 = wave * 32, nb0 = wave * 2;      // N-quarter per wave
    const int a0 = blockIdx.x * MTS;

    const short* W0h = &g_w[EW0H]; const short* W0l = &g_w[EW0L];

#pragma unroll
    for (int it = 0; it < 4; ++it) {
        const int flat = it * 1024 + tid * 4;
        const int r = flat >> 7, f = flat & 127;
        float4 v = {0.f, 0.f, 0.f, 0.f};
        if (a0 + r < N) v = *(const float4*)(x + (size_t)(a0 + r) * DF + f);
        unsigned h0, l0, h1, l1;
        cvt2(v.x, v.y, h0, l0);
        cvt2(v.z, v.w, h1, l1);
        *(uint2*)&s_hi[r][f] = make_uint2(h0, h1);
        *(uint2*)&s_lo[r][f] = make_uint2(l0, l1);
    }
    __syncthreads();

    float4v acc[2][2] = {};
    mm_tile_t<2, 2>(acc, s_hi, s_lo, W0h, W0l, 0, nb0, quad, lq);   // P: kblk 0..3
#pragma unroll
    for (int mt = 0; mt < 2; ++mt)
#pragma unroll
        for (int i = 0; i < 4; ++i) {
            const int a = a0 + mt * 16 + quad * 4 + i;
            if (a < N)
#pragma unroll
                for (int nt = 0; nt < 2; ++nt)
                    g_P[(size_t)a * DF + n0 + nt * 16 + lq] = acc[mt][nt][i];
#pragma unroll
            for (int nt = 0; nt < 2; ++nt) acc[mt][nt][i] = 0.f;
        }
    mm_tile_t<2, 2>(acc, s_hi, s_lo, W0h, W0l, 4, nb0, quad, lq);   // Q: kblk 4..7
#pragma unroll
    for (int mt = 0; mt < 2; ++mt)
#pragma unroll
        for (int i = 0; i < 4; ++i) {
            const int a = a0 + mt * 16 + quad * 4 + i;
            if (a < N)
#pragma unroll
                for (int nt = 0; nt < 2; ++nt)
                    g_Q[(size_t)a * DF + n0 + nt * 16 + lq] = acc[mt][nt][i];
        }
}

// ---------------- edge helpers ----------------
__device__ __forceinline__ void load_idx(int (&rr)[4][4], int (&sr)[4][4],
                                         const int* __restrict__ recv,
                                         const int* __restrict__ send,
                                         int e0, int E, int quad, bool ok)
{
#pragma unroll
    for (int mt = 0; mt < 4; ++mt)
#pragma unroll
        for (int i = 0; i < 4; ++i) {
            const int e = e0 + mt * 16 + quad * 4 + i;
            const bool v = ok && (e < E);
            rr[mt][i] = v ? recv[e] : 0;
            sr[mt][i] = v ? send[e] : 0;
        }
}

__device__ __forceinline__ void gather_pq(float (&pqs)[4][2][4],
                                          const int (&rr)[4][4], const int (&sr)[4][4],
                                          int n0, int lq)
{
    float tp[4][2][4], tq[4][2][4];
#pragma unroll
    for (int mt = 0; mt < 4; ++mt)
#pragma unroll
        for (int i = 0; i < 4; ++i) {
            const float* Pr = g_P + (size_t)rr[mt][i] * DF + n0 + lq;
            const float* Qr = g_Q + (size_t)sr[mt][i] * DF + n0 + lq;
#pragma unroll
            for (int nt = 0; nt < 2; ++nt) {
                tp[mt][nt][i] = Pr[nt * 16];
                tq[mt][nt][i] = Qr[nt * 16];
            }
        }
#pragma unroll
    for (int mt = 0; mt < 4; ++mt)
#pragma unroll
        for (int nt = 0; nt < 2; ++nt)
#pragma unroll
            for (int i = 0; i < 4; ++i)
                pqs[mt][nt][i] = tp[mt][nt][i] + tq[mt][nt][i];
}

// ---------------- fused edge MLP + LN + chunk-sum (persistent, prefetching) ----------------
__launch_bounds__(256, 3)
__global__ void edge_kernel(
    const float* __restrict__ edge_attr,
    const int* __restrict__ recv, const int* __restrict__ send,
    const float* __restrict__ b0, const float* __restrict__ b1, const float* __restrict__ b2,
    const float* __restrict__ gamma, const float* __restrict__ beta,
    int E, int ntiles)
{
    __shared__ short s_hi[MT][136];
    __shared__ short s_lo[MT][136];
    __shared__ float spS[MT][4], spSS[MT][4];   // per-row quarter sums
    __shared__ float cs[MT][8];                 // per-row per-chunk gamma-dot

    const int tid = threadIdx.x;
    const int wave = tid >> 6, lane = tid & 63;
    const int quad = lane >> 4, lq = lane & 15;
    const int n0 = wave * 32, nb0 = wave * 2;   // N-quarter per wave, M = all 64 rows

    const short* W0h = &g_w[EW0H]; const short* W0l = &g_w[EW0L];
    const short* W1h = &g_w[EW1H]; const short* W1l = &g_w[EW1L];
    const short* W2h = &g_w[EW2H]; const short* W2l = &g_w[EW2L];

    // uniform per-thread constants (hoisted across tiles)
    float bl0[2], bl1[2], gl[2], bb2[2];
#pragma unroll
    for (int nt = 0; nt < 2; ++nt) {
        bl0[nt] = b0[n0 + nt * 16 + lq];
        bl1[nt] = b1[n0 + nt * 16 + lq];
        gl[nt]  = gamma[n0 + nt * 16 + lq];
        bb2[nt] = b2[n0 + nt * 16 + lq];
    }

    const int nbk = gridDim.x;
    int t = blockIdx.x;

    // prologue: idx + PQ for first tile
    int rr[4][4], sr[4][4];
    float pqs[4][2][4];
    load_idx(rr, sr, recv, send, t * MT, E, quad, t < ntiles);
    gather_pq(pqs, rr, sr, n0, lq);

    for (; t < ntiles; t += nbk) {
        const int e0 = t * MT;
        const int tn = t + nbk;

        // idx for NEXT tile (latency hidden under phase C + mm0)
        load_idx(rr, sr, recv, send, tn * MT, E, quad, tn < ntiles);

        // ---- phase C: edge_attr tile -> bf16 hi/lo staging ----
        const float* easrc = edge_attr + (size_t)e0 * DF;
        float4 eav[8];
#pragma unroll
        for (int it = 0; it < 8; ++it) {
            const int flat = it * 1024 + tid * 4;
            float4 z = {0.f, 0.f, 0.f, 0.f};
            eav[it] = (e0 + (flat >> 7) < E) ? *(const float4*)(easrc + flat) : z;
        }
#pragma unroll
        for (int it = 0; it < 8; ++it) {
            const int flat = it * 1024 + tid * 4;
            const int rw = flat >> 7, c = flat & 127;
            unsigned h0, l0, h1, l1;
            cvt2(eav[it].x, eav[it].y, h0, l0);
            cvt2(eav[it].z, eav[it].w, h1, l1);
            *(uint2*)&s_hi[rw][c] = make_uint2(h0, h1);
            *(uint2*)&s_lo[rw][c] = make_uint2(l0, l1);
        }
        __syncthreads();

        // acc := P+Q (prefetched); mm0 accumulates ea @ W0c on top
        float4v acc[4][2];
#pragma unroll
        for (int mt = 0; mt < 4; ++mt)
#pragma unroll
            for (int nt = 0; nt < 2; ++nt) {
                float4v tv;
#pragma unroll
                for (int i = 0; i < 4; ++i) tv[i] = pqs[mt][nt][i];
                acc[mt][nt] = tv;
            }
        mm_tile_t<4, 2>(acc, s_hi, s_lo, W0h, W0l, 8, nb0, quad, lq);

        // prefetch NEXT tile's P+Q (drains at the barrier below, overlapped with mm0)
        gather_pq(pqs, rr, sr, n0, lq);

        __syncthreads();
        relu_store_t<4, 2>(acc, s_hi, s_lo, bl0, n0, quad, lq);
        __syncthreads();
        mm_tile_t<4, 2>(acc, s_hi, s_lo, W1h, W1l, 0, nb0, quad, lq);
        __syncthreads();
        relu_store_t<4, 2>(acc, s_hi, s_lo, bl1, n0, quad, lq);
        __syncthreads();
        mm_tile_t<4, 2>(acc, s_hi, s_lo, W2h, W2l, 0, nb0, quad, lq);

        // ---- LN pass 1: quarter stats + chunk gamma-dots ----
#pragma unroll
        for (int mt = 0; mt < 4; ++mt)
#pragma unroll
            for (int i = 0; i < 4; ++i) {
                float v[2], vs, vss;
                v[0] = acc[mt][0][i] + bb2[0];
                v[1] = acc[mt][1][i] + bb2[1];
                vs = v[0] + v[1];
                vss = v[0] * v[0] + v[1] * v[1];
                vs  += __shfl_xor(vs, 1);  vs  += __shfl_xor(vs, 2);
                vs  += __shfl_xor(vs, 4);  vs  += __shfl_xor(vs, 8);
                vss += __shfl_xor(vss, 1); vss += __shfl_xor(vss, 2);
                vss += __shfl_xor(vss, 4); vss += __shfl_xor(vss, 8);
                float cd[2];
#pragma unroll
                for (int nt = 0; nt < 2; ++nt) {
                    float c = v[nt] * gl[nt];
                    c += __shfl_xor(c, 1); c += __shfl_xor(c, 2);
                    c += __shfl_xor(c, 4); c += __shfl_xor(c, 8);
                    cd[nt] = c;
                }
                if (lq == 0) {
                    const int row = mt * 16 + quad * 4 + i;
                    spS[row][wave] = vs;
                    spSS[row][wave] = vss;
                    cs[row][nb0 + 0] = cd[0];
                    cs[row][nb0 + 1] = cd[1];
                }
            }
        __syncthreads();

        // ---- pass 2: finalize LN chunk sums -> node_in ----
        for (int cell = tid; cell < MT * 8; cell += 256) {
            const int rw = cell >> 3, c = cell & 7;
            const float mu  = (spS[rw][0] + spS[rw][1] + spS[rw][2] + spS[rw][3]) * (1.f / 128.f);
            const float var = (spSS[rw][0] + spSS[rw][1] + spSS[rw][2] + spSS[rw][3]) * (1.f / 128.f) - mu * mu;
            const float inv = rsqrtf(var + LNEPS);
            const int ee = e0 + rw;
            if (ee < E)
                g_nodein[(size_t)ee * 8 + c] = inv * (cs[rw][c] - mu * g_sgs[c]) + g_sbs[c];
        }
    }
}

// ---------------- fused node MLP + LN ----------------
__launch_bounds__(256, 4)
__global__ void node_kernel(
    float* __restrict__ out,
    const float* __restrict__ b0, const float* __restrict__ b1, const float* __restrict__ b2,
    const float* __restrict__ gamma, const float* __restrict__ beta,
    int N)
{
    __shared__ short s_hi[MTS][136];
    __shared__ short s_lo[MTS][136];
    __shared__ float spS[MTS][4], spSS[MTS][4];

    const int tid = threadIdx.x;
    const int wave = tid >> 6, lane = tid & 63;
    const int quad = lane >> 4, lq = lane & 15;
    const int n0 = wave * 32, nb0 = wave * 2;   // N-quarter per wave
    const int a0 = blockIdx.x * MTS;

    const short* W0h = &g_w[NW0H]; const short* W0l = &g_w[NW0L];
    const short* W1h = &g_w[NW1H]; const short* W1l = &g_w[NW1L];
    const short* W2h = &g_w[NW2H]; const short* W2l = &g_w[NW2L];

    float bl0[2], bl1[2], gl[2], btl[2], bb[2];
#pragma unroll
    for (int nt = 0; nt < 2; ++nt) {
        bl0[nt] = b0[n0 + nt * 16 + lq];
        bl1[nt] = b1[n0 + nt * 16 + lq];
        gl[nt]  = gamma[n0 + nt * 16 + lq];
        btl[nt] = beta[n0 + nt * 16 + lq];
        bb[nt]  = b2[n0 + nt * 16 + lq];
    }

#pragma unroll
    for (int it = 0; it < 4; ++it) {
        const int flat = it * 1024 + tid * 4;
        const int r = flat >> 7, f = flat & 127;
        float4 v = {0.f, 0.f, 0.f, 0.f};
        if (a0 + r < N) v = *(const float4*)(g_nodein + (size_t)(a0 + r) * DF + f);
        unsigned h0, l0, h1, l1;
        cvt2(v.x, v.y, h0, l0);
        cvt2(v.z, v.w, h1, l1);
        *(uint2*)&s_hi[r][f] = make_uint2(h0, h1);
        *(uint2*)&s_lo[r][f] = make_uint2(l0, l1);
    }
    __syncthreads();

    float4v acc[2][2] = {};
    mm_tile_t<2, 2>(acc, s_hi, s_lo, W0h, W0l, 0, nb0, quad, lq);
    __syncthreads();
    relu_store_t<2, 2>(acc, s_hi, s_lo, bl0, n0, quad, lq);
    __syncthreads();
    mm_tile_t<2, 2>(acc, s_hi, s_lo, W1h, W1l, 0, nb0, quad, lq);
    __syncthreads();
    relu_store_t<2, 2>(acc, s_hi, s_lo, bl1, n0, quad, lq);
    __syncthreads();
    mm_tile_t<2, 2>(acc, s_hi, s_lo, W2h, W2l, 0, nb0, quad, lq);

    // LN pass 1: quarter stats
#pragma unroll
    for (int mt = 0; mt < 2; ++mt)
#pragma unroll
        for (int i = 0; i < 4; ++i) {
            float v0 = acc[mt][0][i] + bb[0];
            float v1 = acc[mt][1][i] + bb[1];
            float vs = v0 + v1, vss = v0 * v0 + v1 * v1;
            vs  += __shfl_xor(vs, 1);  vs  += __shfl_xor(vs, 2);
            vs  += __shfl_xor(vs, 4);  vs  += __shfl_xor(vs, 8);
            vss += __shfl_xor(vss, 1); vss += __shfl_xor(vss, 2);
            vss += __shfl_xor(vss, 4); vss += __shfl_xor(vss, 8);
            if (lq == 0) {
                const int row = mt * 16 + quad * 4 + i;
                spS[row][wave] = vs;
                spSS[row][wave] = vss;
            }
        }
    __syncthreads();

#pragma unroll
    for (int mt = 0; mt < 2; ++mt)
#pragma unroll
        for (int i = 0; i < 4; ++i) {
            const int row = mt * 16 + quad * 4 + i;
            const int a = a0 + row;
            if (a < N) {
                const float mu  = (spS[row][0] + spS[row][1] + spS[row][2] + spS[row][3]) * (1.f / 128.f);
                const float var = (spSS[row][0] + spSS[row][1] + spSS[row][2] + spSS[row][3]) * (1.f / 128.f) - mu * mu;
                const float inv = rsqrtf(var + LNEPS);
#pragma unroll
                for (int nt = 0; nt < 2; ++nt) {
                    const float v = acc[mt][nt][i] + bb[nt];
                    out[(size_t)a * DF + n0 + nt * 16 + lq] = (v - mu) * inv * gl[nt] + btl[nt];
                }
            }
        }
}

extern "C" void kernel_launch(void* const* d_in, const int* in_sizes, int n_in,
                              void* d_out, int out_size, void* d_ws, size_t ws_size,
                              hipStream_t stream)
{
    const float* x   = (const float*)d_in[0];
    const float* ea  = (const float*)d_in[1];
    const int* recv  = (const int*)d_in[2];
    const int* send  = (const int*)d_in[3];
    const float* eW0 = (const float*)d_in[5];
    const float* eb0 = (const float*)d_in[6];
    const float* eW1 = (const float*)d_in[7];
    const float* eb1 = (const float*)d_in[8];
    const float* eW2 = (const float*)d_in[9];
    const float* eb2 = (const float*)d_in[10];
    const float* eg  = (const float*)d_in[11];
    const float* ebt = (const float*)d_in[12];
    const float* nW0 = (const float*)d_in[13];
    const float* nb0 = (const float*)d_in[14];
    const float* nW1 = (const float*)d_in[15];
    const float* nb1 = (const float*)d_in[16];
    const float* nW2 = (const float*)d_in[17];
    const float* nb2 = (const float*)d_in[18];
    const float* ng  = (const float*)d_in[19];
    const float* nbt = (const float*)d_in[20];

    const int E = in_sizes[2];
    const int N = in_sizes[0] / DF;
    const int ntiles = (E + MT - 1) / MT;
    const int gblk = ntiles < EGRID ? ntiles : EGRID;

    WConvArgs wa;
    wa.W[0] = eW0; wa.din[0] = 384;
    wa.W[1] = eW1; wa.din[1] = 128;
    wa.W[2] = eW2; wa.din[2] = 128;
    wa.W[3] = nW0; wa.din[3] = 128;
    wa.W[4] = nW1; wa.din[4] = 128;
    wa.W[5] = nW2; wa.din[5] = 128;
    wa.g = eg; wa.bt = ebt;
    wconv_all<<<513, 256, 0, stream>>>(wa);

    pq_kernel<<<(N + MTS - 1) / MTS, 256, 0, stream>>>(x, N);

    edge_kernel<<<gblk, 256, 0, stream>>>(
        ea, recv, send, eb0, eb1, eb2, eg, ebt, E, ntiles);
    node_kernel<<<(N + MTS - 1) / MTS, 256, 0, stream>>>(
        (float*)d_out, nb0, nb1, nb2, ng, nbt, N);
}